// Round 1
// baseline (1487.449 us; speedup 1.0000x reference)
//
#include <hip/hip_runtime.h>

#define TT 8192
#define BB 512
#define HH 16

// Single-wave sequential GRU scan for batch element 511 only.
// Lane layout (wave 0):
//   lanes  0-15 : r-gate rows of w_hh  (and final h_new computation for unit i)
//   lanes 16-31 : z-gate rows
//   lanes 32-47 : n-gate rows
//   lanes 48-52 : fc_w rows (projection y = fc_w @ h + fc_b, pipelined 1 step behind)
// h_t lives in 16 SGPRs (readlane), so one 16-FMA chain serves all lanes.
__global__ __launch_bounds__(256, 1) void gru_scan_kernel(
    const float* __restrict__ x, const float* __restrict__ w_ih,
    const float* __restrict__ w_hh, const float* __restrict__ b_ih,
    const float* __restrict__ b_hh, const float* __restrict__ fc_w,
    const float* __restrict__ fc_b, float* __restrict__ out)
{
    __shared__ float xs[TT + 8];
    const int tid = threadIdx.x;
    // stage x[:,511,0] into LDS (coalesced-ish strided gather, one time)
    #pragma unroll 4
    for (int i = tid; i < TT; i += 256) xs[i] = x[i * BB + (BB - 1)];
    if (tid < 8) xs[TT + tid] = 0.0f;   // pad for the t+1 prefetch read
    __syncthreads();
    if (tid >= 64) return;              // waves 1-3 done (no barriers after this)

    const int lane = tid;

    // ---- per-lane constants ----
    float wv[HH];
    float cinit = 0.0f;   // chain init (biases folded)
    float xmul  = 0.0f;   // coefficient of x_t folded into chain init
    float xa = 0.0f, xc = 0.0f;  // lane i<16: n-gate x-part coeffs (w_ih[32+i], b_ih[32+i])
    if (lane < 48) {
        #pragma unroll
        for (int k = 0; k < HH; ++k) wv[k] = w_hh[lane * HH + k];
        if (lane < 32) { cinit = b_ih[lane] + b_hh[lane]; xmul = w_ih[lane]; }
        else           { cinit = b_hh[lane]; }             // n-gate: b_ih/x handled separately
    } else if (lane < 53) {
        #pragma unroll
        for (int k = 0; k < HH; ++k) wv[k] = fc_w[(lane - 48) * HH + k];
        cinit = fc_b[lane - 48];
    } else {
        #pragma unroll
        for (int k = 0; k < HH; ++k) wv[k] = 0.0f;
    }
    if (lane < HH) { xa = w_ih[32 + lane]; xc = b_ih[32 + lane]; }

    // h state, wave-uniform (compiler keeps these in SGPRs via readlane)
    float sh[HH];
    #pragma unroll
    for (int k = 0; k < HH; ++k) sh[k] = 0.0f;

    float hv = 0.0f;        // lane i's own h element (valid on lanes 0-15)
    float xt = xs[0];

    for (int t = 0; t < TT; ++t) {
        float xt_nx = xs[t + 1];   // prefetch next step's x (off critical path)

        // ---- matvec: acc = cinit + xmul*x_t + w_row . h  (4 split accumulators) ----
        float a0 = __builtin_fmaf(xt, xmul, cinit);
        a0 = __builtin_fmaf(sh[0],  wv[0],  a0);
        a0 = __builtin_fmaf(sh[1],  wv[1],  a0);
        a0 = __builtin_fmaf(sh[2],  wv[2],  a0);
        a0 = __builtin_fmaf(sh[3],  wv[3],  a0);
        float a1 = sh[4] * wv[4];
        a1 = __builtin_fmaf(sh[5],  wv[5],  a1);
        a1 = __builtin_fmaf(sh[6],  wv[6],  a1);
        a1 = __builtin_fmaf(sh[7],  wv[7],  a1);
        float a2 = sh[8] * wv[8];
        a2 = __builtin_fmaf(sh[9],  wv[9],  a2);
        a2 = __builtin_fmaf(sh[10], wv[10], a2);
        a2 = __builtin_fmaf(sh[11], wv[11], a2);
        float a3 = sh[12] * wv[12];
        a3 = __builtin_fmaf(sh[13], wv[13], a3);
        a3 = __builtin_fmaf(sh[14], wv[14], a3);
        a3 = __builtin_fmaf(sh[15], wv[15], a3);
        float acc = (a0 + a1) + (a2 + a3);

        // sigmoid on all lanes (meaningful on 0-31): 1/(1+e^-x), native exp+rcp
        float sg = __builtin_amdgcn_rcpf(1.0f + __expf(-acc));
        // n-gate x part, computed on lane i directly (coeffs preloaded) — avoids a 3rd shuffle
        float xn = __builtin_fmaf(xt, xa, xc);

        float zv  = __shfl_xor(sg,  16);   // lane i<16 <- sigmoid(z preact) from lane i+16
        float hgn = __shfl_xor(acc, 32);   // lane i<16 <- n-gate hg from lane i+32

        // n = tanh(xn + r*hgn) ; tanh(p) = 1 - 2/(exp(2p)+1)  (saturates correctly at +-inf)
        float pn = __builtin_fmaf(sg, hgn, xn);
        float e2 = __expf(pn + pn);
        float nv = __builtin_fmaf(-2.0f, __builtin_amdgcn_rcpf(e2 + 1.0f), 1.0f);

        // h_new = (1-z)*n + z*h = n + z*(h-n)
        float hnew = __builtin_fmaf(zv, hv - nv, nv);
        hv = hnew;   // only lanes 0-15 hold meaningful h; garbage elsewhere is unused

        // redistribute h_t to SGPRs for next step's chain
        #pragma unroll
        for (int k = 0; k < HH; ++k)
            sh[k] = __uint_as_float(__builtin_amdgcn_readlane(__float_as_uint(hnew), k));

        // fc lanes' chain result this step = fc_w @ h_{t-1} + fc_b = y_{t-1}
        if (t > 0) {
            if (lane >= 48 && lane < 53)
                out[(t - 1) * 5 + (lane - 48)] = acc;
        }
        xt = xt_nx;
    }

    // epilogue: y_{T-1} from final h
    float accf = cinit;
    #pragma unroll
    for (int k = 0; k < HH; ++k) accf = __builtin_fmaf(sh[k], wv[k], accf);
    if (lane >= 48 && lane < 53)
        out[(TT - 1) * 5 + (lane - 48)] = accf;
}

extern "C" void kernel_launch(void* const* d_in, const int* in_sizes, int n_in,
                              void* d_out, int out_size, void* d_ws, size_t ws_size,
                              hipStream_t stream) {
    const float* x    = (const float*)d_in[0];
    const float* w_ih = (const float*)d_in[1];
    const float* w_hh = (const float*)d_in[2];
    const float* b_ih = (const float*)d_in[3];
    const float* b_hh = (const float*)d_in[4];
    const float* fc_w = (const float*)d_in[5];
    const float* fc_b = (const float*)d_in[6];
    float* out = (float*)d_out;
    gru_scan_kernel<<<dim3(1), dim3(256), 0, stream>>>(
        x, w_ih, w_hh, b_ih, b_hh, fc_w, fc_b, out);
}